// Round 9
// baseline (688.468 us; speedup 1.0000x reference)
//
#include <hip/hip_runtime.h>
#include <math.h>

#define NEG_SLOPE 0.2f

typedef __attribute__((ext_vector_type(8))) short short8;
typedef __attribute__((ext_vector_type(4))) float float4v;

__device__ __forceinline__ void atomAddF(float* p, float v) {
    unsafeAtomicAdd(p, v);   // HW global_atomic_add_f32 on gfx950
}
__device__ __forceinline__ unsigned short f2bf(float f) {
    unsigned u = __float_as_uint(f);
    unsigned r = (u + 0x7FFFu + ((u >> 16) & 1u)) >> 16;   // RNE
    return (unsigned short)r;
}
__device__ __forceinline__ float bf2f(unsigned short b) {
    return __uint_as_float((unsigned)b << 16);
}

// ================= CSR build (counting sort by dst) =================
__global__ void hist_kernel(const int* __restrict__ dst, int* __restrict__ cnt, int E) {
    int e = blockIdx.x * blockDim.x + threadIdx.x;
    if (e < E) atomicAdd(&cnt[dst[e]], 1);
}

__global__ void scan1_kernel(const int* __restrict__ cnt, int* __restrict__ incl,
                             int* __restrict__ bsum, int n) {
    __shared__ int s[256];
    int t = threadIdx.x, i = blockIdx.x * 256 + t;
    int v = (i < n) ? cnt[i] : 0;
    s[t] = v; __syncthreads();
    for (int o = 1; o < 256; o <<= 1) {
        int u = (t >= o) ? s[t - o] : 0;
        __syncthreads(); s[t] += u; __syncthreads();
    }
    if (i < n) incl[i] = s[t];
    if (t == 255) bsum[blockIdx.x] = s[255];
}

__global__ void scan2_kernel(int* __restrict__ bsum, int nb) {
    __shared__ int s[512];
    int t = threadIdx.x;
    int v = (t < nb) ? bsum[t] : 0;
    s[t] = v; __syncthreads();
    for (int o = 1; o < 512; o <<= 1) {
        int u = (t >= o) ? s[t - o] : 0;
        __syncthreads(); s[t] += u; __syncthreads();
    }
    if (t < nb) bsum[t] = s[t] - v;   // exclusive
}

__global__ void scan3_kernel(const int* __restrict__ incl, const int* __restrict__ cnt,
                             const int* __restrict__ bsum, int* __restrict__ rowptr,
                             int* __restrict__ cursor, int n, int E) {
    int i = blockIdx.x * blockDim.x + threadIdx.x;
    if (i < n) {
        int v = incl[i] - cnt[i] + bsum[i >> 8];
        rowptr[i] = v; cursor[i] = v;
    } else if (i == n) {
        rowptr[n] = E;
    }
}

__global__ void scatter_kernel(const int* __restrict__ dst, int* __restrict__ cursor,
                               int* __restrict__ perm, int E) {
    int e = blockIdx.x * blockDim.x + threadIdx.x;
    if (e < E) { int pos = atomicAdd(&cursor[dst[e]], 1); perm[pos] = e; }
}

// pkhw[i] = rel*N + src ; pkatt[i] = src*R + rel   (CSR order)
__global__ void pack_kernel(const int* __restrict__ perm, const int* __restrict__ rel,
                            const int* __restrict__ src, unsigned* __restrict__ pkhw,
                            unsigned* __restrict__ pkatt, int E, int N, int R) {
    int i = blockIdx.x * blockDim.x + threadIdx.x;
    if (i < E) {
        int e = perm[i];
        int r = rel[e], s = src[e];
        pkhw[i]  = (unsigned)(r * N + s);
        pkatt[i] = (unsigned)(s * R + r);
    }
}

// ================= per-layer prep =================
// fp32 -> bf16 row conversion
__global__ void conv64_kernel(const float* __restrict__ in, unsigned short* __restrict__ out,
                              size_t n) {
    size_t i = (size_t)blockIdx.x * blockDim.x + threadIdx.x;
    if (i < n) out[i] = f2bf(in[i]);
}

// WbfT[r][e][k] = bf16(W[r][k][e])
__global__ void wconv_kernel(const float* __restrict__ W, unsigned short* __restrict__ WbfT,
                             int R) {
    int i = blockIdx.x * blockDim.x + threadIdx.x;
    if (i >= R * 4096) return;
    int r = i >> 12, rem = i & 4095, k = rem >> 6, e = rem & 63;
    WbfT[((size_t)(r * 64 + e)) * 64 + k] = f2bf(W[i]);
}

// Vbpad[r][0][d]=bf16(sum_e W[r,d,e]a_src[r,e]); row1 = a_dst; rows 2..15 zeroed by memset
__global__ void compute_v_kernel(const float* __restrict__ W,
                                 const float* __restrict__ a_src,
                                 const float* __restrict__ a_dst,
                                 unsigned short* __restrict__ Vbpad, int R) {
    int idx = blockIdx.x * blockDim.x + threadIdx.x;   // r*64+d
    if (idx >= R * 64) return;
    int r = idx >> 6, d = idx & 63;
    const float* Wr = W + idx * 64;
    const float* as = a_src + r * 64;
    const float* ad = a_dst + r * 64;
    float s = 0.f, t = 0.f;
    for (int e = 0; e < 64; e++) { float w = Wr[e]; s = fmaf(w, as[e], s); t = fmaf(w, ad[e], t); }
    Vbpad[((size_t)r * 16 + 0) * 64 + d] = f2bf(s);
    Vbpad[((size_t)r * 16 + 1) * 64 + d] = f2bf(t);
}

// ================= fused hW GEMM + attention (bf16 MFMA, no LDS, no barriers) ===
// A[m=lane&15][k=8*quad+j], B[n=lane&15][k=8*quad+j], D[row=4*quad+reg][col=lane&15]
__global__ __launch_bounds__(256) void hw_att_kernel(
        const unsigned short* __restrict__ hb, const unsigned short* __restrict__ WbfT,
        const unsigned short* __restrict__ Vbpad,
        unsigned short* __restrict__ hWb, float* __restrict__ attS, float* __restrict__ attD,
        int N, int R, int r0, int r1, int doAtt) {
    int t = threadIdx.x;
    int w = t >> 6, lane = t & 63;
    int quad = lane >> 4, m = lane & 15;
    int row = blockIdx.x * 64 + w * 16 + m;
    short8 a0 = {}, a1 = {};
    if (row < N) {
        a0 = *(const short8*)&hb[(size_t)row * 64 + quad * 8];
        a1 = *(const short8*)&hb[(size_t)row * 64 + 32 + quad * 8];
    }
    int nodeBase = blockIdx.x * 64 + w * 16 + quad * 4;

    for (int r = r0; r < r1; r++) {
        const unsigned short* Bp = WbfT + (size_t)r * 4096;
        size_t outR = (size_t)(r - r0) * N * 64;
#pragma unroll
        for (int c = 0; c < 4; c++) {
            short8 b0 = *(const short8*)&Bp[(c * 16 + m) * 64 + quad * 8];
            short8 b1 = *(const short8*)&Bp[(c * 16 + m) * 64 + 32 + quad * 8];
            float4v acc = {0.f, 0.f, 0.f, 0.f};
            acc = __builtin_amdgcn_mfma_f32_16x16x32_bf16(a0, b0, acc, 0, 0, 0);
            acc = __builtin_amdgcn_mfma_f32_16x16x32_bf16(a1, b1, acc, 0, 0, 0);
#pragma unroll
            for (int reg = 0; reg < 4; reg++) {
                int node = nodeBase + reg;
                if (node < N)
                    hWb[outR + (size_t)node * 64 + c * 16 + m] = f2bf(acc[reg]);
            }
        }
        if (doAtt) {
            const unsigned short* Vp = Vbpad + (size_t)r * 16 * 64;
            short8 v0 = *(const short8*)&Vp[m * 64 + quad * 8];
            short8 v1 = *(const short8*)&Vp[m * 64 + 32 + quad * 8];
            float4v av = {0.f, 0.f, 0.f, 0.f};
            av = __builtin_amdgcn_mfma_f32_16x16x32_bf16(a0, v0, av, 0, 0, 0);
            av = __builtin_amdgcn_mfma_f32_16x16x32_bf16(a1, v1, av, 0, 0, 0);
            if (m < 2) {
                float* o = (m == 0) ? attS : attD;
#pragma unroll
                for (int reg = 0; reg < 4; reg++) {
                    int node = nodeBase + reg;
                    if (node < N) o[(size_t)node * R + r] = av[reg];
                }
            }
        }
    }
}

// fallback attention (only used when hWb must be chunked)
#define HPAD 68
__global__ __launch_bounds__(256) void att_gemm_b_kernel(
        const unsigned short* __restrict__ hb, const unsigned short* __restrict__ Vbpad,
        float* __restrict__ attS, float* __restrict__ attD, int N, int R) {
    __shared__ float hl[64 * HPAD];
    int t = threadIdx.x, n0 = blockIdx.x * 64;
    for (int i = t; i < 4096; i += 256) {
        int row = i >> 6, d = i & 63;
        int node = n0 + row;
        hl[row * HPAD + d] = (node < N) ? bf2f(hb[(size_t)node * 64 + d]) : 0.f;
    }
    __syncthreads();
    for (int p = t; p < 64 * R; p += 256) {
        int node = p / R, r = p - node * R;
        int gn = n0 + node;
        if (gn >= N) continue;
        float s = 0.f, dd = 0.f;
        for (int d = 0; d < 64; d++) {
            float hv = hl[node * HPAD + d];
            s  = fmaf(hv, bf2f(Vbpad[((size_t)r * 16 + 0) * 64 + d]), s);
            dd = fmaf(hv, bf2f(Vbpad[((size_t)r * 16 + 1) * 64 + d]), dd);
        }
        attS[(size_t)gn * R + r] = s;
        attD[(size_t)gn * R + r] = dd;
    }
}

// ====== fused softmax + aggregation v2: wave per dst, precomputed indices ======
__global__ __launch_bounds__(256) void aggsoft2_kernel(
        const int* __restrict__ rowptr, const unsigned* __restrict__ pkatt,
        const unsigned* __restrict__ pkhw,
        const float* __restrict__ attS, const float* __restrict__ attD,
        const unsigned short* __restrict__ hWb, float* __restrict__ agg,
        unsigned short* __restrict__ hbOut, float* __restrict__ poolOut,
        const int* __restrict__ poolSeg, int poolStride,
        int n, int shR, unsigned r0N, unsigned r1N, int isFirst, int isLast) {
    int g = blockIdx.x * blockDim.x + threadIdx.x;
    int wv = g >> 6, lane = g & 63;
    if (wv >= n) return;
    int start = rowptr[wv], end = rowptr[wv + 1];
    int deg = end - start;
    unsigned msk = (1u << shR) - 1u;
    float acc = isFirst ? 0.f : agg[(size_t)wv * 64 + lane];

    if (deg > 0 && deg <= 64) {
        int i = start + lane;
        bool act = i < end;
        unsigned pa = 0, ph = 0;
        if (act) { pa = pkatt[i]; ph = pkhw[i]; }
        float sc = -INFINITY;
        if (act) {
            sc = attS[pa] + attD[((unsigned)wv << shR) + (pa & msk)];
            sc = sc > 0.f ? sc : NEG_SLOPE * sc;
        }
        float m = sc;
        for (int o = 32; o; o >>= 1) m = fmaxf(m, __shfl_xor(m, o));
        float ex = act ? expf(sc - m) : 0.f;
        float sum = ex;
        for (int o = 32; o; o >>= 1) sum += __shfl_xor(sum, o);
        float a = ex / (sum + 1e-9f);
        for (int k = 0; k < deg; k++) {
            unsigned pp = (unsigned)__shfl((int)ph, k);
            float aa = __shfl(a, k);
            if (pp >= r0N && pp < r1N)
                acc = fmaf(aa, bf2f(hWb[((size_t)(pp - r0N) << 6) + lane]), acc);
        }
    } else if (deg > 64) {
        float m = -INFINITY;
        for (int base = start; base < end; base += 64) {
            int i = base + lane;
            if (i < end) {
                unsigned pa = pkatt[i];
                float sc = attS[pa] + attD[((unsigned)wv << shR) + (pa & msk)];
                sc = sc > 0.f ? sc : NEG_SLOPE * sc;
                m = fmaxf(m, sc);
            }
        }
        for (int o = 32; o; o >>= 1) m = fmaxf(m, __shfl_xor(m, o));
        float sum = 0.f;
        for (int base = start; base < end; base += 64) {
            int i = base + lane;
            if (i < end) {
                unsigned pa = pkatt[i];
                float sc = attS[pa] + attD[((unsigned)wv << shR) + (pa & msk)];
                sc = sc > 0.f ? sc : NEG_SLOPE * sc;
                sum += expf(sc - m);
            }
        }
        for (int o = 32; o; o >>= 1) sum += __shfl_xor(sum, o);
        float inv = 1.f / (sum + 1e-9f);
        for (int i = start; i < end; i++) {
            unsigned pa = pkatt[i], ph = pkhw[i];   // wave-uniform
            float sc = attS[pa] + attD[((unsigned)wv << shR) + (pa & msk)];
            sc = sc > 0.f ? sc : NEG_SLOPE * sc;
            float aa = expf(sc - m) * inv;
            if (ph >= r0N && ph < r1N)
                acc = fmaf(aa, bf2f(hWb[((size_t)(ph - r0N) << 6) + lane]), acc);
        }
    }

    if (isLast) {
        acc = acc > 0.f ? acc : expm1f(acc);
        if (hbOut) hbOut[(size_t)wv * 64 + lane] = f2bf(acc);
        if (poolOut) atomAddF(&poolOut[(size_t)poolSeg[wv] * poolStride + lane], acc);
    } else {
        agg[(size_t)wv * 64 + lane] = acc;
    }
}

// feat[mol2rxn[m], 64:128] += mol[m]
__global__ void readout_mol_kernel(const float* __restrict__ mol,
                                   const int* __restrict__ mol2rxn,
                                   float* __restrict__ feat, int M) {
    int i = blockIdx.x * blockDim.x + threadIdx.x;
    if (i >= M * 64) return;
    int m = i >> 6, d = i & 63;
    atomAddF(&feat[(size_t)mol2rxn[m] * 128 + 64 + d], mol[i]);
}

// ================= MLP head: LDS-tiled GEMM =================
#define APAD 36
__global__ __launch_bounds__(256) void fc_gemm_kernel(
        const float* __restrict__ A, const float* __restrict__ B,
        const float* __restrict__ bias, const float* __restrict__ prelu,
        float* __restrict__ C, int M, int N, int K, int mode) {
    __shared__ float Al[64 * APAD];
    __shared__ float Bl[32 * 64];
    int t = threadIdx.x;
    int n0 = blockIdx.x * 64, m0 = blockIdx.y * 64;
    int e4 = (t & 15) * 4;
    int n4 = (t >> 4) * 4;
    float acc[4][4] = {};

    for (int k0 = 0; k0 < K; k0 += 32) {
        {
            const float4* Ag = (const float4*)A;
#pragma unroll
            for (int i = 0; i < 2; i++) {
                int idx = t + i * 256;
                int row = idx >> 3, c4 = idx & 7;
                float4 v = Ag[(size_t)(m0 + row) * (K >> 2) + (k0 >> 2) + c4];
                float* p = &Al[row * APAD + c4 * 4];
                p[0] = v.x; p[1] = v.y; p[2] = v.z; p[3] = v.w;
            }
        }
        {
#pragma unroll
            for (int i = 0; i < 2; i++) {
                int idx = t + i * 256;
                int kk = idx >> 4, c4 = (idx & 15) * 4;
                int col = n0 + c4;
                float4 v;
                const float* Brow = B + (size_t)(k0 + kk) * N;
                if (col + 3 < N) v = *(const float4*)&Brow[col];
                else {
                    v.x = (col + 0 < N) ? Brow[col + 0] : 0.f;
                    v.y = (col + 1 < N) ? Brow[col + 1] : 0.f;
                    v.z = (col + 2 < N) ? Brow[col + 2] : 0.f;
                    v.w = 0.f;
                }
                *(float4*)&Bl[kk * 64 + c4] = v;
            }
        }
        __syncthreads();
        for (int d = 0; d < 32; d += 4) {
            float4 wv[4], hv[4];
#pragma unroll
            for (int dd = 0; dd < 4; dd++) wv[dd] = *(const float4*)&Bl[(d + dd) * 64 + e4];
#pragma unroll
            for (int i = 0; i < 4; i++) hv[i] = *(const float4*)&Al[(n4 + i) * APAD + d];
#pragma unroll
            for (int i = 0; i < 4; i++) {
                const float hvv[4] = {hv[i].x, hv[i].y, hv[i].z, hv[i].w};
#pragma unroll
                for (int dd = 0; dd < 4; dd++) {
                    const float* wp = (const float*)&wv[dd];
#pragma unroll
                    for (int j = 0; j < 4; j++) acc[i][j] = fmaf(hvv[dd], wp[j], acc[i][j]);
                }
            }
        }
        __syncthreads();
    }

    float p = mode ? *prelu : 0.f;
#pragma unroll
    for (int i = 0; i < 4; i++) {
        int row = m0 + n4 + i;
#pragma unroll
        for (int j = 0; j < 4; j++) {
            int col = n0 + e4 + j;
            if (col < N) {
                float v = acc[i][j] + bias[col];
                if (mode) v = v > 0.f ? v : p * v;
                C[(size_t)row * N + col] = v;
            }
        }
    }
}

// ================= launch =================
extern "C" void kernel_launch(void* const* d_in, const int* in_sizes, int n_in,
                              void* d_out, int out_size, void* d_ws, size_t ws_size,
                              hipStream_t stream) {
    const float* node_feats = (const float*)d_in[0];
    const int*   edge_src   = (const int*)d_in[1];
    const int*   edge_dst   = (const int*)d_in[2];
    const int*   edge_rel   = (const int*)d_in[3];
    const int*   node2mol   = (const int*)d_in[4];
    const int*   rxn_src    = (const int*)d_in[5];
    const int*   rxn_dst    = (const int*)d_in[6];
    const int*   rxn_rel    = (const int*)d_in[7];
    const int*   mol2rxn    = (const int*)d_in[8];
    const float* W1     = (const float*)d_in[9];
    const float* a_src1 = (const float*)d_in[10];
    const float* a_dst1 = (const float*)d_in[11];
    const float* W2     = (const float*)d_in[12];
    const float* a_src2 = (const float*)d_in[13];
    const float* a_dst2 = (const float*)d_in[14];
    const float* Wr     = (const float*)d_in[15];
    const float* a_srcr = (const float*)d_in[16];
    const float* a_dstr = (const float*)d_in[17];
    const float* w_fc1  = (const float*)d_in[18];
    const float* b_fc1  = (const float*)d_in[19];
    const float* prelu1 = (const float*)d_in[20];
    const float* w_fc2  = (const float*)d_in[21];
    const float* b_fc2  = (const float*)d_in[22];

    const int N = 100000, E = 800000, M = 5000, ER = 40000;

    // ---- workspace layout ----
    float* ws = (float*)d_ws;
    unsigned short* hb0 = (unsigned short*)ws;          // 6.4M ush (12.8 MB)
    unsigned short* hb1 = hb0 + 6400000;                // 6.4M ush
    float* attS = (float*)(hb1 + 6400000);              // 800K f
    float* attD = attS + 800000;                        // 800K f
    unsigned* pkhw  = (unsigned*)(attD + 800000);       // 800K
    unsigned* pkatt = pkhw + 800000;                    // 800K
    float* mol  = (float*)(pkatt + 800000);             // 320K f
    unsigned short* molb = (unsigned short*)(mol + 320000);  // 320K ush
    float* feat = (float*)(molb + 320000);              // 131072 f
    float* hm   = feat + 131072;                        // 524288 f
    unsigned short* WbfT  = (unsigned short*)(hm + 524288);  // 32768 ush
    unsigned short* Vbpad = WbfT + 32768;               // 8192 ush
    int* rowptr = (int*)(Vbpad + 8192);                 // 100008
    float* agg  = (float*)(rowptr + 100008);            // 6.4M f (chunk carry)
    // scratch (CSR build) aliases the head of the hWb region:
    char* tail = (char*)(agg + 6400000);
    int* cnt    = (int*)tail;                           // 100000
    int* incl   = cnt + 100000;
    int* bsum   = incl + 100000;                        // 512
    int* cursor = bsum + 512;
    int* perm   = cursor + 100000;                      // 800000
    unsigned short* hWb = (unsigned short*)tail;        // overlays scratch (disjoint in time)

    size_t tailBytes = (ws_size > (size_t)(tail - (char*)d_ws)) ? ws_size - (size_t)(tail - (char*)d_ws) : 0;
    size_t availUsh = tailBytes / 2;

    auto buildCSR = [&](const int* dstArr, const int* srcArr, const int* relArr,
                        int n, int e, int R) {
        hipMemsetAsync(cnt, 0, (size_t)n * sizeof(int), stream);
        hist_kernel<<<dim3((e + 255) / 256), 256, 0, stream>>>(dstArr, cnt, e);
        int nb = (n + 255) / 256;
        scan1_kernel<<<dim3(nb), 256, 0, stream>>>(cnt, incl, bsum, n);
        scan2_kernel<<<dim3(1), 512, 0, stream>>>(bsum, nb);
        scan3_kernel<<<dim3((n + 256) / 256), 256, 0, stream>>>(incl, cnt, bsum, rowptr, cursor, n, e);
        scatter_kernel<<<dim3((e + 255) / 256), 256, 0, stream>>>(dstArr, cursor, perm, e);
        pack_kernel<<<dim3((e + 255) / 256), 256, 0, stream>>>(perm, relArr, srcArr, pkhw, pkatt, e, n, R);
    };

    auto rgat = [&](const unsigned short* hin, int n, const float* W,
                    const float* as, const float* ad, int R, int shR,
                    unsigned short* hbOut, float* poolOut, const int* poolSeg, int poolStride) {
        hipMemsetAsync(Vbpad, 0, (size_t)R * 16 * 64 * 2, stream);
        compute_v_kernel<<<dim3((R * 64 + 63) / 64), 64, 0, stream>>>(W, as, ad, Vbpad, R);
        wconv_kernel<<<dim3((R * 4096 + 255) / 256), 256, 0, stream>>>(W, WbfT, R);

        size_t perRel = (size_t)n * 64;
        int chunk = (int)(availUsh / perRel);
        if (chunk < 1) chunk = 1;
        if (chunk > R) chunk = R;
        int fused = (chunk == R) ? 1 : 0;
        if (!fused)
            att_gemm_b_kernel<<<dim3((n + 63) / 64), 256, 0, stream>>>(hin, Vbpad, attS, attD, n, R);
        for (int r0 = 0; r0 < R; r0 += chunk) {
            int r1 = r0 + chunk; if (r1 > R) r1 = R;
            hw_att_kernel<<<dim3((n + 63) / 64), 256, 0, stream>>>(
                hin, WbfT, Vbpad, hWb, attS, attD, n, R, r0, r1, fused);
            aggsoft2_kernel<<<dim3(((size_t)n * 64 + 255) / 256), 256, 0, stream>>>(
                rowptr, pkatt, pkhw, attS, attD, hWb, agg,
                hbOut, poolOut, poolSeg, poolStride,
                n, shR, (unsigned)((size_t)r0 * n), (unsigned)((size_t)r1 * n),
                r0 == 0 ? 1 : 0, r1 == R ? 1 : 0);
        }
    };

    // ---- atom graph ----
    buildCSR(edge_dst, edge_src, edge_rel, N, E, 8);
    conv64_kernel<<<dim3((N * 64 + 255) / 256), 256, 0, stream>>>(node_feats, hb0, (size_t)N * 64);
    // layer 1: out -> hb1 (bf16)
    rgat(hb0, N, W1, a_src1, a_dst1, 8, 3, hb1, nullptr, nullptr, 0);
    // layer 2: out -> mol pooling (fp32 atomics), no h2 stored
    hipMemsetAsync(mol, 0, (size_t)M * 64 * sizeof(float), stream);
    rgat(hb1, N, W2, a_src2, a_dst2, 8, 3, nullptr, mol, node2mol, 64);

    // ---- reaction graph ----
    conv64_kernel<<<dim3((M * 64 + 255) / 256), 256, 0, stream>>>(mol, molb, (size_t)M * 64);
    buildCSR(rxn_dst, rxn_src, rxn_rel, M, ER, 4);
    hipMemsetAsync(feat, 0, (size_t)1024 * 128 * sizeof(float), stream);
    rgat(molb, M, Wr, a_srcr, a_dstr, 4, 2, nullptr, feat, mol2rxn, 128);
    readout_mol_kernel<<<dim3((M * 64 + 255) / 256), 256, 0, stream>>>(mol, mol2rxn, feat, M);

    // ---- MLP head ----
    fc_gemm_kernel<<<dim3(8, 16), 256, 0, stream>>>(feat, w_fc1, b_fc1, prelu1, hm, 1024, 512, 128, 1);
    fc_gemm_kernel<<<dim3(11, 16), 256, 0, stream>>>(hm, w_fc2, b_fc2, nullptr, (float*)d_out, 1024, 703, 512, 0);
}